// Round 4
// baseline (4328.842 us; speedup 1.0000x reference)
//
#include <hip/hip_runtime.h>

// Echo-state RNN, B=32, T=2048, NH=512, NI=NO=1.  W_hh ~90% exact zeros.
// One workgroup (CU) per batch; thread p owns row perm[p] (rows sorted by nnz
// desc so each wave's slot count ~= its local max). Sparse rows in REGISTERS
// (static indexing only). NEW: a deterministic ballot-based scheduler assigns
// each lane's entries to gather slots so that each LDS bank gets <=2 requests
// per wave per slot (2/bank is free) -- near-zero bank conflicts, vs 2389
// conflict-cycles/step with naive ordering. z-reduction on VALU pipe via DPP.

#define NH   512
#define TT   2048
#define BB   32
#define PAD  96          // schedule slot cap (>= max row nnz ~76 + slack)
#define PADH (PAD/2)

// ---------------------------------------------------------------------------
// A: nnz per row (wave-per-row ballot count)
// ---------------------------------------------------------------------------
__global__ __launch_bounds__(512) void count_nnz(
    const float* __restrict__ Whh, int* __restrict__ nnz) {
  const int wib  = threadIdx.x >> 6;
  const int lane = threadIdx.x & 63;
  const int row  = blockIdx.x * 8 + wib;
  const float* wrow = Whh + (size_t)row * NH;
  int cnt = 0;
  for (int c = 0; c < NH / 64; ++c)
    cnt += __popcll(__ballot(wrow[c * 64 + lane] != 0.0f));
  if (lane == 0) nnz[row] = cnt;
}

// ---------------------------------------------------------------------------
// B: rank rows by nnz descending (stable). perm[p] = row at sorted pos p.
// ---------------------------------------------------------------------------
__global__ __launch_bounds__(512) void sort_rows(
    const int* __restrict__ nnz, int* __restrict__ perm) {
  __shared__ int nl[NH];
  const int j = threadIdx.x;
  const int my = nnz[j];
  nl[j] = my;
  __syncthreads();
  int r = 0;
  const int4* p4 = (const int4*)nl;
  for (int i = 0; i < NH / 4; ++i) {
    int4 v = p4[i];
    const int base = i * 4;
    r += (v.x > my) || (v.x == my && base + 0 < j);
    r += (v.y > my) || (v.y == my && base + 1 < j);
    r += (v.z > my) || (v.z == my && base + 2 < j);
    r += (v.w > my) || (v.w == my && base + 3 < j);
  }
  perm[r] = j;
}

// ---------------------------------------------------------------------------
// C: bank-conflict-free gather schedule. One block of 512 = 8 waves; wave w
// schedules its own 64 lanes. Per slot: each unplaced lane proposes its
// most-populated remaining bank; acceptance resolved deterministically via
// 32 static ballots (rank < capacity 2 per bank per wave). Rejected lanes
// retry other banks. Near the PAD cap, force mode ignores capacity so every
// lane places one entry per slot (guaranteed completion, s <= PAD).
// Output: vals/offs entry-major [slot*NH + p]; cntw[w] = slot count of wave w.
// ---------------------------------------------------------------------------
__global__ __launch_bounds__(512) void build_schedule(
    const float* __restrict__ Whh, const int* __restrict__ perm,
    float* __restrict__ vals, unsigned* __restrict__ offs,
    int* __restrict__ cntw) {
  __shared__ unsigned short occ[512][34];   // [34]: pad to kill scan conflicts
  const int p    = threadIdx.x;
  const int lane = p & 63;
  const int wid  = p >> 6;
  const int row  = perm[p];
  const float* wrow = Whh + (size_t)row * NH;

  // occupancy mask per bank: bit m set iff W[row][b + 32m] != 0
  int remaining = 0;
  for (int b = 0; b < 32; ++b) {
    unsigned m16 = 0;
    for (int m = 0; m < 16; ++m)
      m16 |= (wrow[b + 32 * m] != 0.0f) ? (1u << m) : 0u;
    occ[p][b] = (unsigned short)m16;
    remaining += __popc(m16);
  }

  const unsigned long long mylow = (1ull << lane) - 1ull;

  int s = 0;
  while (__ballot(remaining > 0) != 0ull) {
    // wave-max remaining (for the force-mode trigger)
    int maxrem = remaining;
    #pragma unroll
    for (int o = 32; o > 0; o >>= 1) {
      int t = __shfl_xor(maxrem, o);
      maxrem = t > maxrem ? t : maxrem;
    }
    const bool force = (PAD - s) <= maxrem;

    unsigned excl = 0, loadA = 0, loadB = 0;  // per-bank load: A=(>=1), B=(>=2)
    bool placed = false;
    int  myb = 0;

    for (int round = 0; round < 33; ++round) {
      bool want = (remaining > 0) && !placed;
      int b_l = 0, bestc = 0;
      if (want) {
        #pragma unroll
        for (int b = 0; b < 32; ++b) {
          bool ok = force || (!((excl >> b) & 1u) && !((loadB >> b) & 1u));
          int c = ok ? __popc((unsigned)occ[p][b]) : 0;
          if (c > bestc) { bestc = c; b_l = b; }
        }
        want = bestc > 0;
      }
      if (__ballot(want) == 0ull) break;
      #pragma unroll
      for (int b = 0; b < 32; ++b) {
        unsigned long long mb = __ballot(want && (b_l == b));
        if (mb != 0ull) {
          const int ld  = (int)((loadA >> b) & 1u) + (int)((loadB >> b) & 1u);
          const int cap = 2 - ld;
          if (want && b_l == b) {
            int rank = (int)__popcll(mb & mylow);
            if (force || rank < cap) { placed = true; myb = b; }
            else                     excl |= (1u << b);
          }
          int nl = ld + (int)__popcll(mb);
          if (nl > 2) nl = 2;
          loadA = (loadA & ~(1u << b)) | ((nl >= 1) ? (1u << b) : 0u);
          loadB = (loadB & ~(1u << b)) | ((nl >= 2) ? (1u << b) : 0u);
        }
      }
    }

    float v = 0.0f; unsigned col = 0u;
    if (placed) {
      unsigned m16 = (unsigned)occ[p][myb];
      int m = __ffs(m16) - 1;                 // lowest unconsumed column
      col = (unsigned)(myb + 32 * m);
      occ[p][myb] = (unsigned short)(m16 & (m16 - 1u));
      v = wrow[col];
      --remaining;
    }
    vals[s * NH + p] = v;                      // idle lanes: harmless 0 * t[0]
    offs[s * NH + p] = col;
    ++s;
  }
  if (lane == 0) cntw[wid] = s;
  for (int e = s; e < PAD; ++e) {              // zero-fill tail slots
    vals[e * NH + p] = 0.0f;
    offs[e * NH + p] = 0u;
  }
}

// ---------------------------------------------------------------------------
// DPP wave-64 sum reduction on the VALU pipe; lane 63 ends with the full sum.
// ---------------------------------------------------------------------------
template <int CTRL, int RM>
__device__ __forceinline__ float dppadd(float v) {
  int t = __builtin_amdgcn_update_dpp(0, __float_as_int(v), CTRL, RM, 0xF, true);
  return v + __int_as_float(t);
}
__device__ __forceinline__ float wave_sum_lane63(float v) {
  v = dppadd<0xB1,  0xF>(v);   // quad_perm [1,0,3,2]
  v = dppadd<0x4E,  0xF>(v);   // quad_perm [2,3,0,1]
  v = dppadd<0x141, 0xF>(v);   // row_half_mirror
  v = dppadd<0x140, 0xF>(v);   // row_mirror
  v = dppadd<0x142, 0xA>(v);   // row_bcast15 -> rows 1,3
  v = dppadd<0x143, 0xC>(v);   // row_bcast31 -> rows 2,3
  return v;                    // lane 63 = sum of 64
}

// ---------------------------------------------------------------------------
// Main: one block per batch, 512 threads, 2048 sequential steps.
// ---------------------------------------------------------------------------
__global__ __launch_bounds__(512, 2) void esn_steps(
    const float* __restrict__ x,   const float* __restrict__ h0,
    const float* __restrict__ Wih, const float* __restrict__ Whz,
    const float* __restrict__ Wzh, const float* __restrict__ vals,
    const unsigned* __restrict__ offs, const int* __restrict__ perm,
    const int* __restrict__ cntw, float* __restrict__ out) {
  __shared__ float t_lds[2][NH];              // tanh(h), double-buffered
  __shared__ float x_lds[TT];                 // this batch's input row
  __shared__ __align__(16) float red[2][8];   // cross-wave partials for z

  const int p    = threadIdx.x;               // sorted position owned
  const int b    = blockIdx.x;
  const int lane = p & 63;
  const int wid  = p >> 6;
  const int row  = perm[p];                   // actual hidden unit

  for (int i = p; i < TT; i += NH) x_lds[i] = x[(size_t)b * TT + i];

  // wave-uniform slot count, rounded to the 8-wide chunking (tail slots are
  // zero-filled by the scheduler, so over-read is harmless).
  int cw = __builtin_amdgcn_readfirstlane((cntw[wid] + 7) & ~7);

  // this position's scheduled entries -> registers (entry-major, coalesced)
  float    wval[PAD];
  unsigned woff[PADH];                        // two u16 columns per reg
  #pragma unroll
  for (int e = 0; e < PAD; ++e) wval[e] = vals[e * NH + p];
  #pragma unroll
  for (int ep = 0; ep < PADH; ++ep) {
    unsigned lo = offs[(2 * ep) * NH + p];
    unsigned hi = offs[(2 * ep + 1) * NH + p];
    woff[ep] = lo | (hi << 16);
  }

  const float w_ih = Wih[row];
  const float w_hz = Whz[row];
  const float w_zh = Wzh[row];
  float h = h0[(size_t)b * NH + row];

  float* oz = out + (size_t)b * TT;                        // z region [B,T,1]
  float* oh = out + (size_t)BB * TT + (size_t)b * TT * NH; // h region [B,T,NH]

  // ---- init: t[0] = tanh(h0); z_prev = sum(tanh(h0) * Whz) ----
  float th0 = tanhf(h);
  t_lds[0][row] = th0;
  float pz = wave_sum_lane63(th0 * w_hz);
  if (lane == 63) red[0][wid] = pz;
  __syncthreads();
  float4 i0 = *(const float4*)&red[0][0];
  float4 i1 = *(const float4*)&red[0][4];
  float z_prev = ((i0.x + i0.y) + (i0.z + i0.w)) + ((i1.x + i1.y) + (i1.z + i1.w));

  // ---- 2048 sequential steps, one barrier each ----
  for (int s = 0; s < TT; ++s) {
    const int rd = s & 1, wr = rd ^ 1;
    const float* t_rd = t_lds[rd];

    // sparse dot; fully static unroll, each 8-chunk guarded by a
    // wave-uniform scalar branch (no data-dependent break -> no spill).
    float d0 = 0.f, d1 = 0.f, d2 = 0.f, d3 = 0.f;
    #pragma unroll
    for (int e = 0; e < PAD; e += 8) {
      if (e < cw) {
        const unsigned q0 = woff[(e >> 1) + 0];
        const unsigned q1 = woff[(e >> 1) + 1];
        const unsigned q2 = woff[(e >> 1) + 2];
        const unsigned q3 = woff[(e >> 1) + 3];
        d0 = fmaf(wval[e + 0], t_rd[q0 & 0xFFFFu], d0);
        d1 = fmaf(wval[e + 1], t_rd[q0 >> 16],     d1);
        d2 = fmaf(wval[e + 2], t_rd[q1 & 0xFFFFu], d2);
        d3 = fmaf(wval[e + 3], t_rd[q1 >> 16],     d3);
        d0 = fmaf(wval[e + 4], t_rd[q2 & 0xFFFFu], d0);
        d1 = fmaf(wval[e + 5], t_rd[q2 >> 16],     d1);
        d2 = fmaf(wval[e + 6], t_rd[q3 & 0xFFFFu], d2);
        d3 = fmaf(wval[e + 7], t_rd[q3 >> 16],     d3);
      }
    }
    float dot = (d0 + d1) + (d2 + d3);

    float xp   = x_lds[s] * w_ih;
    float dhdt = ((dot - h) + xp) + z_prev * w_zh;
    float hn   = h + 0.1f * dhdt;             // alpha = dt/tau = 0.1
    float thn  = tanhf(hn);

    t_lds[wr][row] = thn;                     // scatter (unique indices)
    oh[s * NH + row] = hn;                    // global scatter within 2KB

    float pzs = wave_sum_lane63(thn * w_hz);  // VALU-pipe reduction
    if (lane == 63) red[wr][wid] = pzs;

    __syncthreads();

    float4 r0 = *(const float4*)&red[wr][0];
    float4 r1 = *(const float4*)&red[wr][4];
    float z = ((r0.x + r0.y) + (r0.z + r0.w)) + ((r1.x + r1.y) + (r1.z + r1.w));
    if (p == 0) oz[s] = z;

    z_prev = z;
    h = hn;
  }
}

// ---------------------------------------------------------------------------
extern "C" void kernel_launch(void* const* d_in, const int* in_sizes, int n_in,
                              void* d_out, int out_size, void* d_ws,
                              size_t ws_size, hipStream_t stream) {
  const float* x   = (const float*)d_in[0];
  const float* h0  = (const float*)d_in[1];
  const float* Wih = (const float*)d_in[2];
  const float* Whh = (const float*)d_in[3];
  const float* Whz = (const float*)d_in[4];
  const float* Wzh = (const float*)d_in[5];
  float* out = (float*)d_out;

  float*    vals = (float*)d_ws;                     // PAD*NH f32 = 192 KB
  unsigned* offs = (unsigned*)(vals + PAD * NH);     // PAD*NH u32 = 192 KB
  int*      nnz  = (int*)(offs + PAD * NH);          // NH
  int*      perm = nnz + NH;                         // NH
  int*      cntw = perm + NH;                        // 8

  hipLaunchKernelGGL(count_nnz, dim3(NH / 8), dim3(512), 0, stream, Whh, nnz);
  hipLaunchKernelGGL(sort_rows, dim3(1), dim3(512), 0, stream, nnz, perm);
  hipLaunchKernelGGL(build_schedule, dim3(1), dim3(512), 0, stream,
                     Whh, perm, vals, offs, cntw);
  hipLaunchKernelGGL(esn_steps, dim3(BB), dim3(512), 0, stream,
                     x, h0, Wih, Whz, Wzh, vals, offs, perm, cntw, out);
}

// Round 5
// 4167.623 us; speedup vs baseline: 1.0387x; 1.0387x over previous
//
#include <hip/hip_runtime.h>

// Echo-state RNN, B=32, T=2048, NH=512, NI=NO=1.  W_hh ~90% exact zeros.
// One workgroup (CU) per batch; thread p owns row perm[p] (rows sorted by nnz
// desc). Sparse rows in REGISTERS (static indexing only). Gather slots are
// scheduled so each LDS bank gets <=1 request PER HALF-WAVE per slot (the LDS
// pipe runs wave64 as two 32-lane phases; <=2/bank only free when split
// across halves -- round 4 proved <=2-per-wave is worthless). Scheduler runs
// 8 blocks (one wave each), occupancy masks in registers, winner arbitration
// via deterministic LDS atomicMin. In-loop barrier waits lgkmcnt only (no
// vmcnt drain of the per-step global h-store).

#define NH   512
#define TT   2048
#define BB   32
#define PAD  104         // slot cap: lane-deg max ~76, half-bank-deg max ~68
#define PADH (PAD/2)
#define SENT 64

// ---------------------------------------------------------------------------
// A: nnz per row (wave-per-row ballot count)
// ---------------------------------------------------------------------------
__global__ __launch_bounds__(512) void count_nnz(
    const float* __restrict__ Whh, int* __restrict__ nnz) {
  const int wib  = threadIdx.x >> 6;
  const int lane = threadIdx.x & 63;
  const int row  = blockIdx.x * 8 + wib;
  const float* wrow = Whh + (size_t)row * NH;
  int cnt = 0;
  for (int c = 0; c < NH / 64; ++c)
    cnt += __popcll(__ballot(wrow[c * 64 + lane] != 0.0f));
  if (lane == 0) nnz[row] = cnt;
}

// ---------------------------------------------------------------------------
// B: rank rows by nnz descending (stable). perm[p] = row at sorted pos p.
// ---------------------------------------------------------------------------
__global__ __launch_bounds__(512) void sort_rows(
    const int* __restrict__ nnz, int* __restrict__ perm) {
  __shared__ int nl[NH];
  const int j = threadIdx.x;
  const int my = nnz[j];
  nl[j] = my;
  __syncthreads();
  int r = 0;
  const int4* p4 = (const int4*)nl;
  for (int i = 0; i < NH / 4; ++i) {
    int4 v = p4[i];
    const int base = i * 4;
    r += (v.x > my) || (v.x == my && base + 0 < j);
    r += (v.y > my) || (v.y == my && base + 1 < j);
    r += (v.z > my) || (v.z == my && base + 2 < j);
    r += (v.w > my) || (v.w == my && base + 3 < j);
  }
  perm[r] = j;
}

// ---------------------------------------------------------------------------
// C: conflict-free gather schedule, one WAVE per block (grid=8).
// Per slot: unplaced lanes propose their most-populated remaining bank;
// winner per (half,bank) = min proposing lane via LDS atomicMin (then locked
// with -1). Losers exclude that bank and retry (<=33 bounded rounds). Force
// mode near PAD places unconditionally (guaranteed completion, s <= PAD).
// Occupancy masks live in 16 packed u32 REGISTERS (static indexing only).
// ---------------------------------------------------------------------------
__global__ __launch_bounds__(64) void build_schedule(
    const float* __restrict__ Whh, const int* __restrict__ perm,
    float* __restrict__ vals, unsigned* __restrict__ offs,
    int* __restrict__ cntw) {
  __shared__ int claim[2][32];
  const int lane = threadIdx.x;
  const int wid  = blockIdx.x;
  const int p    = wid * 64 + lane;
  const int half = lane >> 5;
  const int row  = perm[p];
  const float* wrow = Whh + (size_t)row * NH;

  // reg r: lo16 = presence mask of bank 2r (bit m <=> col 2r+32m nz),
  //        hi16 = bank 2r+1.
  unsigned occ32[16];
  int remaining = 0;
  unsigned nonempty = 0;
  #pragma unroll
  for (int r = 0; r < 16; ++r) {
    unsigned lo = 0, hi = 0;
    #pragma unroll
    for (int m = 0; m < 16; ++m) {
      lo |= (wrow[(2 * r)     + 32 * m] != 0.f) ? (1u << m) : 0u;
      hi |= (wrow[(2 * r + 1) + 32 * m] != 0.f) ? (1u << m) : 0u;
    }
    occ32[r] = lo | (hi << 16);
    remaining += __popc(lo) + __popc(hi);
    if (lo) nonempty |= 1u << (2 * r);
    if (hi) nonempty |= 1u << (2 * r + 1);
  }

  int s = 0;
  while (__ballot(remaining > 0) != 0ull && s < PAD) {
    int mr = remaining;
    #pragma unroll
    for (int o = 32; o > 0; o >>= 1) {
      int t = __shfl_xor(mr, o);
      mr = t > mr ? t : mr;
    }
    const bool force = (PAD - s) <= mr;

    claim[lane >> 5][lane & 31] = SENT;       // covers both halves
    __builtin_amdgcn_wave_barrier();

    bool placed = false;
    int  mybank = 0;
    unsigned excl = 0;

    for (int round = 0; round < 33; ++round) {
      bool want = (!placed) && (remaining > 0);
      int bl = -1;
      if (want) {
        unsigned cand = nonempty & ~excl;
        if (cand == 0u) { want = false; }
        else if (force) { bl = __ffs(cand) - 1; }
        else {
          int bestc = 0;
          #pragma unroll
          for (int r = 0; r < 16; ++r) {
            unsigned w = occ32[r];
            int c0 = __popc(w & 0xFFFFu);
            int c1 = __popc(w >> 16);
            if (((cand >> (2 * r)) & 1u)     && c0 > bestc) { bestc = c0; bl = 2 * r; }
            if (((cand >> (2 * r + 1)) & 1u) && c1 > bestc) { bestc = c1; bl = 2 * r + 1; }
          }
          if (bl < 0) want = false;
        }
      }
      if (__ballot(want) == 0ull) break;

      bool win = false;
      if (want) {
        if (force) {
          win = true;                         // capacity ignored (rare)
        } else {
          atomicMin(&claim[half][bl], lane);
          __builtin_amdgcn_wave_barrier();
          win = (((volatile int*)claim[half])[bl] == lane);
          if (win) atomicMin(&claim[half][bl], -1);   // lock bank for slot
          else     excl |= 1u << bl;
        }
      }
      __builtin_amdgcn_wave_barrier();
      if (win) { placed = true; mybank = bl; }
    }

    float v = 0.f; unsigned col = 0u;
    if (placed) {                             // consume lowest col of mybank
      #pragma unroll
      for (int r = 0; r < 16; ++r) {
        if (r == (mybank >> 1)) {
          unsigned w   = occ32[r];
          unsigned m16 = (mybank & 1) ? (w >> 16) : (w & 0xFFFFu);
          int m = __ffs(m16) - 1;
          col = (unsigned)(mybank + 32 * m);
          unsigned nm = m16 & (m16 - 1u);
          occ32[r] = (mybank & 1) ? ((w & 0x0000FFFFu) | (nm << 16))
                                  : ((w & 0xFFFF0000u) | nm);
          if (nm == 0u) nonempty &= ~(1u << mybank);
        }
      }
      v = wrow[col];
      --remaining;
    }
    vals[s * NH + p] = v;                     // idle lanes: harmless 0 * t[0]
    offs[s * NH + p] = col;
    ++s;
  }
  if (lane == 0) cntw[wid] = s;
  for (int e = s; e < PAD; ++e) {             // zero-fill tail slots
    vals[e * NH + p] = 0.f;
    offs[e * NH + p] = 0u;
  }
}

// ---------------------------------------------------------------------------
// DPP wave-64 sum reduction on the VALU pipe; lane 63 ends with the full sum.
// ---------------------------------------------------------------------------
template <int CTRL, int RM>
__device__ __forceinline__ float dppadd(float v) {
  int t = __builtin_amdgcn_update_dpp(0, __float_as_int(v), CTRL, RM, 0xF, true);
  return v + __int_as_float(t);
}
__device__ __forceinline__ float wave_sum_lane63(float v) {
  v = dppadd<0xB1,  0xF>(v);   // quad_perm [1,0,3,2]
  v = dppadd<0x4E,  0xF>(v);   // quad_perm [2,3,0,1]
  v = dppadd<0x141, 0xF>(v);   // row_half_mirror
  v = dppadd<0x140, 0xF>(v);   // row_mirror
  v = dppadd<0x142, 0xA>(v);   // row_bcast15 -> rows 1,3
  v = dppadd<0x143, 0xC>(v);   // row_bcast31 -> rows 2,3
  return v;                    // lane 63 = sum of 64
}

// ---------------------------------------------------------------------------
// Main: one block per batch, 512 threads, 2048 sequential steps.
// ---------------------------------------------------------------------------
__global__ __launch_bounds__(512, 2) void esn_steps(
    const float* __restrict__ x,   const float* __restrict__ h0,
    const float* __restrict__ Wih, const float* __restrict__ Whz,
    const float* __restrict__ Wzh, const float* __restrict__ vals,
    const unsigned* __restrict__ offs, const int* __restrict__ perm,
    const int* __restrict__ cntw, float* __restrict__ out) {
  __shared__ float t_lds[2][NH];              // tanh(h), double-buffered
  __shared__ float x_lds[TT];                 // this batch's input row
  __shared__ __align__(16) float red[2][8];   // cross-wave partials for z

  const int p    = threadIdx.x;               // sorted position owned
  const int b    = blockIdx.x;
  const int lane = p & 63;
  const int wid  = p >> 6;
  const int row  = perm[p];                   // actual hidden unit

  for (int i = p; i < TT; i += NH) x_lds[i] = x[(size_t)b * TT + i];

  // wave-uniform slot count, rounded to the 8-wide chunking (tail slots are
  // zero-filled by the scheduler, so over-read is harmless).
  int cw = __builtin_amdgcn_readfirstlane((cntw[wid] + 7) & ~7);

  // scheduled entries -> registers (entry-major, coalesced)
  float    wval[PAD];
  unsigned woff[PADH];                        // two u16 columns per reg
  #pragma unroll
  for (int e = 0; e < PAD; ++e) wval[e] = vals[e * NH + p];
  #pragma unroll
  for (int ep = 0; ep < PADH; ++ep) {
    unsigned lo = offs[(2 * ep) * NH + p];
    unsigned hi = offs[(2 * ep + 1) * NH + p];
    woff[ep] = lo | (hi << 16);
  }

  const float w_ih = Wih[row];
  const float w_hz = Whz[row];
  const float w_zh = Wzh[row];
  float h = h0[(size_t)b * NH + row];

  float* oz = out + (size_t)b * TT;                        // z region [B,T,1]
  float* oh = out + (size_t)BB * TT + (size_t)b * TT * NH; // h region [B,T,NH]

  // ---- init: t[0] = tanh(h0); z_prev = sum(tanh(h0) * Whz) ----
  float th0 = tanhf(h);
  t_lds[0][row] = th0;
  float pz = wave_sum_lane63(th0 * w_hz);
  if (lane == 63) red[0][wid] = pz;
  __syncthreads();
  float4 i0 = *(const float4*)&red[0][0];
  float4 i1 = *(const float4*)&red[0][4];
  float z_prev = ((i0.x + i0.y) + (i0.z + i0.w)) + ((i1.x + i1.y) + (i1.z + i1.w));

  // ---- 2048 sequential steps, one (lgkm-only) barrier each ----
  for (int s = 0; s < TT; ++s) {
    const int rd = s & 1, wr = rd ^ 1;
    const float* t_rd = t_lds[rd];

    // sparse dot; fully static unroll, each 8-chunk guarded by a
    // wave-uniform scalar branch (no data-dependent break -> no spill).
    float d0 = 0.f, d1 = 0.f, d2 = 0.f, d3 = 0.f;
    #pragma unroll
    for (int e = 0; e < PAD; e += 8) {
      if (e < cw) {
        const unsigned q0 = woff[(e >> 1) + 0];
        const unsigned q1 = woff[(e >> 1) + 1];
        const unsigned q2 = woff[(e >> 1) + 2];
        const unsigned q3 = woff[(e >> 1) + 3];
        d0 = fmaf(wval[e + 0], t_rd[q0 & 0xFFFFu], d0);
        d1 = fmaf(wval[e + 1], t_rd[q0 >> 16],     d1);
        d2 = fmaf(wval[e + 2], t_rd[q1 & 0xFFFFu], d2);
        d3 = fmaf(wval[e + 3], t_rd[q1 >> 16],     d3);
        d0 = fmaf(wval[e + 4], t_rd[q2 & 0xFFFFu], d0);
        d1 = fmaf(wval[e + 5], t_rd[q2 >> 16],     d1);
        d2 = fmaf(wval[e + 6], t_rd[q3 & 0xFFFFu], d2);
        d3 = fmaf(wval[e + 7], t_rd[q3 >> 16],     d3);
      }
    }
    float dot = (d0 + d1) + (d2 + d3);

    float xp   = x_lds[s] * w_ih;
    float dhdt = ((dot - h) + xp) + z_prev * w_zh;
    float hn   = h + 0.1f * dhdt;             // alpha = dt/tau = 0.1
    float thn  = tanhf(hn);

    t_lds[wr][row] = thn;                     // scatter (unique indices)
    oh[s * NH + row] = hn;                    // global scatter within 2KB

    float pzs = wave_sum_lane63(thn * w_hz);  // VALU-pipe reduction
    if (lane == 63) red[wr][wid] = pzs;

    // barrier draining LDS only -- do NOT wait vmcnt(0) for the oh store
    asm volatile("s_waitcnt lgkmcnt(0)\n\ts_barrier" ::: "memory");

    float4 r0 = *(const float4*)&red[wr][0];
    float4 r1 = *(const float4*)&red[wr][4];
    float z = ((r0.x + r0.y) + (r0.z + r0.w)) + ((r1.x + r1.y) + (r1.z + r1.w));
    if (p == 0) oz[s] = z;

    z_prev = z;
    h = hn;
  }
}

// ---------------------------------------------------------------------------
extern "C" void kernel_launch(void* const* d_in, const int* in_sizes, int n_in,
                              void* d_out, int out_size, void* d_ws,
                              size_t ws_size, hipStream_t stream) {
  const float* x   = (const float*)d_in[0];
  const float* h0  = (const float*)d_in[1];
  const float* Wih = (const float*)d_in[2];
  const float* Whh = (const float*)d_in[3];
  const float* Whz = (const float*)d_in[4];
  const float* Wzh = (const float*)d_in[5];
  float* out = (float*)d_out;

  float*    vals = (float*)d_ws;                     // PAD*NH f32 = 208 KB
  unsigned* offs = (unsigned*)(vals + PAD * NH);     // PAD*NH u32 = 208 KB
  int*      nnz  = (int*)(offs + PAD * NH);          // NH
  int*      perm = nnz + NH;                         // NH
  int*      cntw = perm + NH;                        // 8

  hipLaunchKernelGGL(count_nnz, dim3(NH / 8), dim3(512), 0, stream, Whh, nnz);
  hipLaunchKernelGGL(sort_rows, dim3(1), dim3(512), 0, stream, nnz, perm);
  hipLaunchKernelGGL(build_schedule, dim3(8), dim3(64), 0, stream,
                     Whh, perm, vals, offs, cntw);
  hipLaunchKernelGGL(esn_steps, dim3(BB), dim3(512), 0, stream,
                     x, h0, Wih, Whz, Wzh, vals, offs, perm, cntw, out);
}

// Round 6
// 2845.563 us; speedup vs baseline: 1.5213x; 1.4646x over previous
//
#include <hip/hip_runtime.h>

// Echo-state RNN, B=32, T=2048, NH=512, NI=NO=1.  W_hh ~90% exact zeros.
// One workgroup (CU) per batch; thread p owns row perm[p] (rows sorted by nnz
// desc). Sparse rows in REGISTERS (static indexing only; u32 element indices,
// no packing -- saves the unpack op; VGPR headroom is free at 8 waves/CU).
// Gather slots scheduled so each LDS bank gets <=1 request per HALF-WAVE per
// slot. Scheduler proposals use lane-ROTATED bank order (decorrelated; round-5
// post-mortem: low-bank tie-breaking caused ~1 placement/round and 1.35 ms of
// scheduling). Step loop unrolled x2 so each half-step reads a constant LDS
// buffer pointer (gather addresses loop-invariant). z-reduction on VALU pipe
// via DPP; in-loop barrier drains lgkmcnt only.

#define NH   512
#define TT   2048
#define BB   32
#define PAD  96
#define SENT 64

// ---------------------------------------------------------------------------
// A: nnz per row (wave-per-row ballot count)
// ---------------------------------------------------------------------------
__global__ __launch_bounds__(512) void count_nnz(
    const float* __restrict__ Whh, int* __restrict__ nnz) {
  const int wib  = threadIdx.x >> 6;
  const int lane = threadIdx.x & 63;
  const int row  = blockIdx.x * 8 + wib;
  const float* wrow = Whh + (size_t)row * NH;
  int cnt = 0;
  for (int c = 0; c < NH / 64; ++c)
    cnt += __popcll(__ballot(wrow[c * 64 + lane] != 0.0f));
  if (lane == 0) nnz[row] = cnt;
}

// ---------------------------------------------------------------------------
// B: rank rows by nnz descending (stable). perm[p] = row at sorted pos p.
// ---------------------------------------------------------------------------
__global__ __launch_bounds__(512) void sort_rows(
    const int* __restrict__ nnz, int* __restrict__ perm) {
  __shared__ int nl[NH];
  const int j = threadIdx.x;
  const int my = nnz[j];
  nl[j] = my;
  __syncthreads();
  int r = 0;
  const int4* p4 = (const int4*)nl;
  for (int i = 0; i < NH / 4; ++i) {
    int4 v = p4[i];
    const int base = i * 4;
    r += (v.x > my) || (v.x == my && base + 0 < j);
    r += (v.y > my) || (v.y == my && base + 1 < j);
    r += (v.z > my) || (v.z == my && base + 2 < j);
    r += (v.w > my) || (v.w == my && base + 3 < j);
  }
  perm[r] = j;
}

// ---------------------------------------------------------------------------
// C: conflict-free gather schedule, one WAVE per block (grid=8).
// Per slot: each unplaced lane proposes its next unconsumed bank in
// lane-rotated order (home = lane&31 -> proposals decorrelated across a
// half-wave). Winner per (half,bank) = min proposing lane via LDS atomicMin,
// then locked with -1 for the slot. Rejected lanes retry (cap 8 rounds).
// Per-lane force mode (slots-left <= remaining) places unconditionally --
// guarantees completion by s == PAD. Occupancy masks in 16 packed u32 regs.
// ---------------------------------------------------------------------------
__global__ __launch_bounds__(64) void build_schedule(
    const float* __restrict__ Whh, const int* __restrict__ perm,
    float* __restrict__ vals, unsigned* __restrict__ offs,
    int* __restrict__ cntw) {
  __shared__ int claim[2][32];
  const int lane = threadIdx.x;
  const int wid  = blockIdx.x;
  const int p    = wid * 64 + lane;
  const int half = lane >> 5;
  const int home = lane & 31;
  const int row  = perm[p];
  const float* wrow = Whh + (size_t)row * NH;

  // reg r: lo16 = presence mask of bank 2r (bit m <=> col 2r+32m nz), hi16 = 2r+1
  unsigned occ32[16];
  int remaining = 0;
  unsigned nonempty = 0;
  #pragma unroll
  for (int r = 0; r < 16; ++r) {
    unsigned lo = 0, hi = 0;
    #pragma unroll
    for (int m = 0; m < 16; ++m) {
      lo |= (wrow[(2 * r)     + 32 * m] != 0.f) ? (1u << m) : 0u;
      hi |= (wrow[(2 * r + 1) + 32 * m] != 0.f) ? (1u << m) : 0u;
    }
    occ32[r] = lo | (hi << 16);
    remaining += __popc(lo) + __popc(hi);
    if (lo) nonempty |= 1u << (2 * r);
    if (hi) nonempty |= 1u << (2 * r + 1);
  }

  int s = 0;
  while (__ballot(remaining > 0) != 0ull) {
    claim[half][home] = SENT;                 // covers both halves x 32 banks
    __builtin_amdgcn_wave_barrier();

    const bool force = (remaining > 0) && ((PAD - s) <= remaining);
    bool placed = false;
    int  mybank = 0;
    unsigned excl = 0;

    for (int round = 0; round < 8; ++round) {
      unsigned cand = (placed || remaining == 0) ? 0u : (nonempty & ~excl);
      bool want = cand != 0u;
      int bl = 0;
      if (want) {                             // rotated-first-set proposal
        unsigned rot = home ? ((cand >> home) | (cand << (32 - home))) : cand;
        bl = (home + __ffs(rot) - 1) & 31;
      }
      if (__ballot(want) == 0ull) break;
      bool win = false;
      if (want) {
        if (force) {
          win = true;                         // unconditional (rare; may conflict)
        } else {
          atomicMin(&claim[half][bl], lane);
          __builtin_amdgcn_wave_barrier();
          int c = ((volatile int*)claim[half])[bl];
          if (c == lane) { win = true; ((volatile int*)claim[half])[bl] = -1; }
          else           excl |= 1u << bl;
        }
      }
      __builtin_amdgcn_wave_barrier();
      if (win) { placed = true; mybank = bl; }
    }

    float v = 0.f; unsigned col = 0u;
    if (placed) {                             // consume lowest col of mybank
      #pragma unroll
      for (int r = 0; r < 16; ++r) {
        if (r == (mybank >> 1)) {
          unsigned w   = occ32[r];
          unsigned m16 = (mybank & 1) ? (w >> 16) : (w & 0xFFFFu);
          int m = __ffs(m16) - 1;
          col = (unsigned)(mybank + 32 * m);
          unsigned nm = m16 & (m16 - 1u);
          occ32[r] = (mybank & 1) ? ((w & 0x0000FFFFu) | (nm << 16))
                                  : ((w & 0xFFFF0000u) | nm);
          if (nm == 0u) nonempty &= ~(1u << mybank);
        }
      }
      v = wrow[col];
      --remaining;
    }
    vals[s * NH + p] = v;                     // idle lanes: harmless 0 * t[0]
    offs[s * NH + p] = col;
    ++s;
  }
  if (lane == 0) cntw[wid] = s;
  for (int e = s; e < PAD; ++e) {             // zero-fill tail slots
    vals[e * NH + p] = 0.f;
    offs[e * NH + p] = 0u;
  }
}

// ---------------------------------------------------------------------------
// DPP wave-64 sum reduction on the VALU pipe; lane 63 ends with the full sum.
// ---------------------------------------------------------------------------
template <int CTRL, int RM>
__device__ __forceinline__ float dppadd(float v) {
  int t = __builtin_amdgcn_update_dpp(0, __float_as_int(v), CTRL, RM, 0xF, true);
  return v + __int_as_float(t);
}
__device__ __forceinline__ float wave_sum_lane63(float v) {
  v = dppadd<0xB1,  0xF>(v);   // quad_perm [1,0,3,2]
  v = dppadd<0x4E,  0xF>(v);   // quad_perm [2,3,0,1]
  v = dppadd<0x141, 0xF>(v);   // row_half_mirror
  v = dppadd<0x140, 0xF>(v);   // row_mirror
  v = dppadd<0x142, 0xA>(v);   // row_bcast15 -> rows 1,3
  v = dppadd<0x143, 0xC>(v);   // row_bcast31 -> rows 2,3
  return v;                    // lane 63 = sum of 64
}

// ---------------------------------------------------------------------------
// Main: one block per batch, 512 threads, 2048 sequential steps (x2 unroll).
// ---------------------------------------------------------------------------
#define ESN_STEP(T_RD, T_WR, RWR, SIDX)                                      \
  {                                                                          \
    float d0 = 0.f, d1 = 0.f, d2 = 0.f, d3 = 0.f;                            \
    _Pragma("unroll")                                                        \
    for (int e = 0; e < PAD; e += 8) {                                       \
      if (e < cw) {                                                          \
        d0 = fmaf(wval[e + 0], T_RD[cidx[e + 0]], d0);                       \
        d1 = fmaf(wval[e + 1], T_RD[cidx[e + 1]], d1);                       \
        d2 = fmaf(wval[e + 2], T_RD[cidx[e + 2]], d2);                       \
        d3 = fmaf(wval[e + 3], T_RD[cidx[e + 3]], d3);                       \
        d0 = fmaf(wval[e + 4], T_RD[cidx[e + 4]], d0);                       \
        d1 = fmaf(wval[e + 5], T_RD[cidx[e + 5]], d1);                       \
        d2 = fmaf(wval[e + 6], T_RD[cidx[e + 6]], d2);                       \
        d3 = fmaf(wval[e + 7], T_RD[cidx[e + 7]], d3);                       \
      }                                                                      \
    }                                                                        \
    float dot  = (d0 + d1) + (d2 + d3);                                      \
    float xp   = x_lds[SIDX] * w_ih;                                         \
    float dhdt = ((dot - h) + xp) + z_prev * w_zh;                           \
    float hn   = h + 0.1f * dhdt;                                            \
    float thn  = tanhf(hn);                                                  \
    T_WR[row] = thn;                                                         \
    oh[(SIDX) * NH + row] = hn;                                              \
    float pzs = wave_sum_lane63(thn * w_hz);                                 \
    if (lane == 63) red[RWR][wid] = pzs;                                     \
    asm volatile("s_waitcnt lgkmcnt(0)\n\ts_barrier" ::: "memory");          \
    float4 r0 = *(const float4*)&red[RWR][0];                                \
    float4 r1 = *(const float4*)&red[RWR][4];                                \
    float z = ((r0.x + r0.y) + (r0.z + r0.w)) + ((r1.x + r1.y) + (r1.z + r1.w)); \
    if (p == 0) oz[SIDX] = z;                                                \
    z_prev = z; h = hn;                                                      \
  }

__global__ __launch_bounds__(512, 2) void esn_steps(
    const float* __restrict__ x,   const float* __restrict__ h0,
    const float* __restrict__ Wih, const float* __restrict__ Whz,
    const float* __restrict__ Wzh, const float* __restrict__ vals,
    const unsigned* __restrict__ offs, const int* __restrict__ perm,
    const int* __restrict__ cntw, float* __restrict__ out) {
  __shared__ float t_lds[2][NH];              // tanh(h), double-buffered
  __shared__ float x_lds[TT];                 // this batch's input row
  __shared__ __align__(16) float red[2][8];   // cross-wave partials for z

  const int p    = threadIdx.x;               // sorted position owned
  const int b    = blockIdx.x;
  const int lane = p & 63;
  const int wid  = p >> 6;
  const int row  = perm[p];                   // actual hidden unit

  float* t0 = t_lds[0];
  float* t1 = t_lds[1];

  for (int i = p; i < TT; i += NH) x_lds[i] = x[(size_t)b * TT + i];

  // wave-uniform slot count, rounded to the 8-wide chunking (tail slots are
  // zero-filled by the scheduler, so over-read is harmless).
  int cw = __builtin_amdgcn_readfirstlane((cntw[wid] + 7) & ~7);

  // scheduled entries -> registers (entry-major, coalesced). Plain u32
  // element indices: no unpack op per gather; addresses loop-invariant.
  float    wval[PAD];
  unsigned cidx[PAD];
  #pragma unroll
  for (int e = 0; e < PAD; ++e) wval[e] = vals[e * NH + p];
  #pragma unroll
  for (int e = 0; e < PAD; ++e) cidx[e] = offs[e * NH + p];

  const float w_ih = Wih[row];
  const float w_hz = Whz[row];
  const float w_zh = Wzh[row];
  float h = h0[(size_t)b * NH + row];

  float* oz = out + (size_t)b * TT;                        // z region [B,T,1]
  float* oh = out + (size_t)BB * TT + (size_t)b * TT * NH; // h region [B,T,NH]

  // ---- init: t0 = tanh(h0); z_prev = sum(tanh(h0) * Whz) ----
  float th0 = tanhf(h);
  t0[row] = th0;
  float pz = wave_sum_lane63(th0 * w_hz);
  if (lane == 63) red[0][wid] = pz;
  __syncthreads();
  float4 i0 = *(const float4*)&red[0][0];
  float4 i1 = *(const float4*)&red[0][4];
  float z_prev = ((i0.x + i0.y) + (i0.z + i0.w)) + ((i1.x + i1.y) + (i1.z + i1.w));

  // ---- 2048 sequential steps, x2 unrolled (constant buffer ptr per body) ----
  for (int s = 0; s < TT; s += 2) {
    ESN_STEP(t0, t1, 1, s);
    ESN_STEP(t1, t0, 0, s + 1);
  }
}

// ---------------------------------------------------------------------------
extern "C" void kernel_launch(void* const* d_in, const int* in_sizes, int n_in,
                              void* d_out, int out_size, void* d_ws,
                              size_t ws_size, hipStream_t stream) {
  const float* x   = (const float*)d_in[0];
  const float* h0  = (const float*)d_in[1];
  const float* Wih = (const float*)d_in[2];
  const float* Whh = (const float*)d_in[3];
  const float* Whz = (const float*)d_in[4];
  const float* Wzh = (const float*)d_in[5];
  float* out = (float*)d_out;

  float*    vals = (float*)d_ws;                     // PAD*NH f32 = 192 KB
  unsigned* offs = (unsigned*)(vals + PAD * NH);     // PAD*NH u32 = 192 KB
  int*      nnz  = (int*)(offs + PAD * NH);          // NH
  int*      perm = nnz + NH;                         // NH
  int*      cntw = perm + NH;                        // 8

  hipLaunchKernelGGL(count_nnz, dim3(NH / 8), dim3(512), 0, stream, Whh, nnz);
  hipLaunchKernelGGL(sort_rows, dim3(1), dim3(512), 0, stream, nnz, perm);
  hipLaunchKernelGGL(build_schedule, dim3(8), dim3(64), 0, stream,
                     Whh, perm, vals, offs, cntw);
  hipLaunchKernelGGL(esn_steps, dim3(BB), dim3(512), 0, stream,
                     x, h0, Wih, Whz, Wzh, vals, offs, perm, cntw, out);
}

// Round 7
// 2640.417 us; speedup vs baseline: 1.6395x; 1.0777x over previous
//
#include <hip/hip_runtime.h>

// Echo-state RNN, B=32, T=2048, NH=512, NI=NO=1.  W_hh ~90% exact zeros.
// One workgroup (CU) per batch; thread p owns row perm[p] (rows sorted by nnz
// desc). Sparse rows in REGISTERS -- first PIN slots pinned via asm (round-6
// VGPR=112 proved the compiler was streaming part of the weights from L2
// every step). Gather slots scheduled so each LDS bank gets <=1 request per
// HALF-WAVE per slot; arbitration priority = remaining entries (round-6
// post-mortem: the old force-mode bypassed the bank constraint for every
// high-degree lane from slot ~20 on -- conflicts never dropped). Gathers are
// 1 ds_read each (byte offsets, buffer base folded into the imm). Fast tanh
// via exp2+rcp. z-reduction on VALU pipe via DPP; barrier drains lgkm only.

#define NH   512
#define TT   2048
#define BB   32
#define PAD  96
#define PIN  80          // slots pinned into VGPRs (2 regs/slot)

// ---------------------------------------------------------------------------
// A: nnz per row (wave-per-row ballot count)
// ---------------------------------------------------------------------------
__global__ __launch_bounds__(512) void count_nnz(
    const float* __restrict__ Whh, int* __restrict__ nnz) {
  const int wib  = threadIdx.x >> 6;
  const int lane = threadIdx.x & 63;
  const int row  = blockIdx.x * 8 + wib;
  const float* wrow = Whh + (size_t)row * NH;
  int cnt = 0;
  for (int c = 0; c < NH / 64; ++c)
    cnt += __popcll(__ballot(wrow[c * 64 + lane] != 0.0f));
  if (lane == 0) nnz[row] = cnt;
}

// ---------------------------------------------------------------------------
// B: rank rows by nnz descending (stable). perm[p] = row at sorted pos p.
// ---------------------------------------------------------------------------
__global__ __launch_bounds__(512) void sort_rows(
    const int* __restrict__ nnz, int* __restrict__ perm) {
  __shared__ int nl[NH];
  const int j = threadIdx.x;
  const int my = nnz[j];
  nl[j] = my;
  __syncthreads();
  int r = 0;
  const int4* p4 = (const int4*)nl;
  for (int i = 0; i < NH / 4; ++i) {
    int4 v = p4[i];
    const int base = i * 4;
    r += (v.x > my) || (v.x == my && base + 0 < j);
    r += (v.y > my) || (v.y == my && base + 1 < j);
    r += (v.z > my) || (v.z == my && base + 2 < j);
    r += (v.w > my) || (v.w == my && base + 3 < j);
  }
  perm[r] = j;
}

// ---------------------------------------------------------------------------
// C: conflict-free gather schedule, one WAVE per block (grid=8).
// Per slot: each unplaced lane proposes its next unconsumed bank in
// lane-rotated order (decorrelated proposals). Winner per (half,bank) =
// max key (remaining<<8 | lane) via LDS atomicMax -> desperate lanes win
// WITHOUT breaking the bank constraint; winner locks the bank (INT_MAX).
// Force backstop (unconditional, may conflict) only when slots-left ==
// remaining -- with priority arbitration it should almost never fire.
// ---------------------------------------------------------------------------
__global__ __launch_bounds__(64) void build_schedule(
    const float* __restrict__ Whh, const int* __restrict__ perm,
    float* __restrict__ vals, unsigned* __restrict__ offs,
    int* __restrict__ cntw) {
  __shared__ int claim[2][32];
  const int lane = threadIdx.x;
  const int wid  = blockIdx.x;
  const int p    = wid * 64 + lane;
  const int half = lane >> 5;
  const int home = lane & 31;
  const int row  = perm[p];
  const float* wrow = Whh + (size_t)row * NH;

  // reg r: lo16 = presence mask of bank 2r (bit m <=> col 2r+32m nz), hi16 = 2r+1
  unsigned occ32[16];
  int remaining = 0;
  unsigned nonempty = 0;
  #pragma unroll
  for (int r = 0; r < 16; ++r) {
    unsigned lo = 0, hi = 0;
    #pragma unroll
    for (int m = 0; m < 16; ++m) {
      lo |= (wrow[(2 * r)     + 32 * m] != 0.f) ? (1u << m) : 0u;
      hi |= (wrow[(2 * r + 1) + 32 * m] != 0.f) ? (1u << m) : 0u;
    }
    occ32[r] = lo | (hi << 16);
    remaining += __popc(lo) + __popc(hi);
    if (lo) nonempty |= 1u << (2 * r);
    if (hi) nonempty |= 1u << (2 * r + 1);
  }

  int s = 0;
  while (__ballot(remaining > 0) != 0ull && s < PAD) {
    claim[half][home] = 0;                    // covers both halves x 32 banks
    __builtin_amdgcn_wave_barrier();

    bool placed = false;
    int  mybank = 0;
    unsigned excl = 0;
    const int key = (remaining << 8) | (lane + 1);

    for (int round = 0; round < 12; ++round) {
      unsigned cand = (placed || remaining == 0) ? 0u : (nonempty & ~excl);
      bool want = cand != 0u;
      int bl = 0;
      if (want) {                             // rotated-first-set proposal
        unsigned rot = home ? ((cand >> home) | (cand << (32 - home))) : cand;
        bl = (home + __ffs(rot) - 1) & 31;
      }
      if (__ballot(want) == 0ull) break;
      if (want) atomicMax(&claim[half][bl], key);
      __builtin_amdgcn_wave_barrier();
      if (want) {
        int c = ((volatile int*)claim[half])[bl];
        if (c == key) {
          placed = true; mybank = bl;
          ((volatile int*)claim[half])[bl] = 0x7FFFFFFF;   // lock for slot
        } else {
          excl |= 1u << bl;
        }
      }
      __builtin_amdgcn_wave_barrier();
    }

    // backstop: must place now or we run out of slots (rare; may conflict)
    if (!placed && remaining > 0 && (PAD - s) <= remaining) {
      placed = true;
      mybank = __ffs(nonempty) - 1;
    }

    float v = 0.f; unsigned col = 0u;
    if (placed) {                             // consume lowest col of mybank
      #pragma unroll
      for (int r = 0; r < 16; ++r) {
        if (r == (mybank >> 1)) {
          unsigned w   = occ32[r];
          unsigned m16 = (mybank & 1) ? (w >> 16) : (w & 0xFFFFu);
          int m = __ffs(m16) - 1;
          col = (unsigned)(mybank + 32 * m);
          unsigned nm = m16 & (m16 - 1u);
          occ32[r] = (mybank & 1) ? ((w & 0x0000FFFFu) | (nm << 16))
                                  : ((w & 0xFFFF0000u) | nm);
          if (nm == 0u) nonempty &= ~(1u << mybank);
        }
      }
      v = wrow[col];
      --remaining;
    }
    vals[s * NH + p] = v;                     // idle lanes: harmless 0 * t[0]
    offs[s * NH + p] = col;
    ++s;
  }
  if (lane == 0) cntw[wid] = s;
  for (int e = s; e < PAD; ++e) {             // zero-fill tail slots
    vals[e * NH + p] = 0.f;
    offs[e * NH + p] = 0u;
  }
}

// ---------------------------------------------------------------------------
// DPP wave-64 sum reduction on the VALU pipe; lane 63 ends with the full sum.
// ---------------------------------------------------------------------------
template <int CTRL, int RM>
__device__ __forceinline__ float dppadd(float v) {
  int t = __builtin_amdgcn_update_dpp(0, __float_as_int(v), CTRL, RM, 0xF, true);
  return v + __int_as_float(t);
}
__device__ __forceinline__ float wave_sum_lane63(float v) {
  v = dppadd<0xB1,  0xF>(v);   // quad_perm [1,0,3,2]
  v = dppadd<0x4E,  0xF>(v);   // quad_perm [2,3,0,1]
  v = dppadd<0x141, 0xF>(v);   // row_half_mirror
  v = dppadd<0x140, 0xF>(v);   // row_mirror
  v = dppadd<0x142, 0xA>(v);   // row_bcast15 -> rows 1,3
  v = dppadd<0x143, 0xC>(v);   // row_bcast31 -> rows 2,3
  return v;                    // lane 63 = sum of 64
}

// fast tanh: (t-1)/(t+1), t = exp(2x), clamp |x|<=9 (tanh(9)=1-2.5e-8).
// ~7 VALU ops vs ~25 for library tanhf; err ~2-3 ulp.
__device__ __forceinline__ float ftanh(float x) {
  float xc = fminf(9.0f, fmaxf(-9.0f, x));
  float t  = __expf(2.0f * xc);
  return (t - 1.0f) * __builtin_amdgcn_rcpf(t + 1.0f);
}

// ---------------------------------------------------------------------------
// Main: one block per batch, 512 threads, 2048 sequential steps (x2 unroll).
// ---------------------------------------------------------------------------
#define GA(T_RD, E) (*(const float*)((const char*)(T_RD) + cidx[E]))

#define ESN_STEP(T_RD, T_WR, RWR, SIDX)                                      \
  {                                                                          \
    float d0 = 0.f, d1 = 0.f, d2 = 0.f, d3 = 0.f;                            \
    _Pragma("unroll")                                                        \
    for (int e = 0; e < PAD; e += 8) {                                       \
      if (e < cw) {                                                          \
        d0 = fmaf(wval[e + 0], GA(T_RD, e + 0), d0);                         \
        d1 = fmaf(wval[e + 1], GA(T_RD, e + 1), d1);                         \
        d2 = fmaf(wval[e + 2], GA(T_RD, e + 2), d2);                         \
        d3 = fmaf(wval[e + 3], GA(T_RD, e + 3), d3);                         \
        d0 = fmaf(wval[e + 4], GA(T_RD, e + 4), d0);                         \
        d1 = fmaf(wval[e + 5], GA(T_RD, e + 5), d1);                         \
        d2 = fmaf(wval[e + 6], GA(T_RD, e + 6), d2);                         \
        d3 = fmaf(wval[e + 7], GA(T_RD, e + 7), d3);                         \
      }                                                                      \
    }                                                                        \
    float dot  = (d0 + d1) + (d2 + d3);                                      \
    float xp   = x_lds[SIDX] * w_ih;                                         \
    float dhdt = ((dot - h) + xp) + z_prev * w_zh;                           \
    float hn   = h + 0.1f * dhdt;                                            \
    float thn  = ftanh(hn);                                                  \
    T_WR[row] = thn;                                                         \
    oh[(SIDX) * NH + row] = hn;                                              \
    float pzs = wave_sum_lane63(thn * w_hz);                                 \
    if (lane == 63) red[RWR][wid] = pzs;                                     \
    asm volatile("s_waitcnt lgkmcnt(0)\n\ts_barrier" ::: "memory");          \
    float4 r0 = *(const float4*)&red[RWR][0];                                \
    float4 r1 = *(const float4*)&red[RWR][4];                                \
    float z = ((r0.x + r0.y) + (r0.z + r0.w)) + ((r1.x + r1.y) + (r1.z + r1.w)); \
    if (p == 0) oz[SIDX] = z;                                                \
    z_prev = z; h = hn;                                                      \
  }

__global__ __launch_bounds__(512, 2) void esn_steps(
    const float* __restrict__ x,   const float* __restrict__ h0,
    const float* __restrict__ Wih, const float* __restrict__ Whz,
    const float* __restrict__ Wzh, const float* __restrict__ vals,
    const unsigned* __restrict__ offs, const int* __restrict__ perm,
    const int* __restrict__ cntw, float* __restrict__ out) {
  __shared__ float t_lds[2][NH];              // tanh(h), double-buffered
  __shared__ float x_lds[TT];                 // this batch's input row
  __shared__ __align__(16) float red[2][8];   // cross-wave partials for z

  const int p    = threadIdx.x;               // sorted position owned
  const int b    = blockIdx.x;
  const int lane = p & 63;
  const int wid  = p >> 6;
  const int row  = perm[p];                   // actual hidden unit

  float* t0 = t_lds[0];
  float* t1 = t_lds[1];

  for (int i = p; i < TT; i += NH) x_lds[i] = x[(size_t)b * TT + i];

  // wave-uniform slot count, rounded to the 8-wide chunking (tail slots are
  // zero-filled by the scheduler, so over-read is harmless).
  int cw = __builtin_amdgcn_readfirstlane((cntw[wid] + 7) & ~7);

  // scheduled entries -> registers (entry-major, coalesced). cidx holds BYTE
  // offsets so each gather is one ds_read with the buffer base as imm offset.
  float    wval[PAD];
  unsigned cidx[PAD];
  #pragma unroll
  for (int e = 0; e < PAD; ++e) {
    wval[e] = vals[e * NH + p];
    cidx[e] = offs[e * NH + p] * 4u;
  }
  // pin the first PIN slots into VGPRs: asm outputs can't be rematerialized
  // from memory, so the compiler must keep them resident (round-6 VGPR=112
  // showed it was re-loading weights from L2 inside the step loop).
  #pragma unroll
  for (int e = 0; e < PIN; ++e)
    asm volatile("" : "+v"(wval[e]), "+v"(cidx[e]));

  const float w_ih = Wih[row];
  const float w_hz = Whz[row];
  const float w_zh = Wzh[row];
  float h = h0[(size_t)b * NH + row];

  float* oz = out + (size_t)b * TT;                        // z region [B,T,1]
  float* oh = out + (size_t)BB * TT + (size_t)b * TT * NH; // h region [B,T,NH]

  // ---- init: t0 = tanh(h0); z_prev = sum(tanh(h0) * Whz) ----
  float th0 = ftanh(h);
  t0[row] = th0;
  float pz = wave_sum_lane63(th0 * w_hz);
  if (lane == 63) red[0][wid] = pz;
  __syncthreads();
  float4 i0 = *(const float4*)&red[0][0];
  float4 i1 = *(const float4*)&red[0][4];
  float z_prev = ((i0.x + i0.y) + (i0.z + i0.w)) + ((i1.x + i1.y) + (i1.z + i1.w));

  // ---- 2048 sequential steps, x2 unrolled (constant buffer ptr per body) ----
  for (int s = 0; s < TT; s += 2) {
    ESN_STEP(t0, t1, 1, s);
    ESN_STEP(t1, t0, 0, s + 1);
  }
}

// ---------------------------------------------------------------------------
extern "C" void kernel_launch(void* const* d_in, const int* in_sizes, int n_in,
                              void* d_out, int out_size, void* d_ws,
                              size_t ws_size, hipStream_t stream) {
  const float* x   = (const float*)d_in[0];
  const float* h0  = (const float*)d_in[1];
  const float* Wih = (const float*)d_in[2];
  const float* Whh = (const float*)d_in[3];
  const float* Whz = (const float*)d_in[4];
  const float* Wzh = (const float*)d_in[5];
  float* out = (float*)d_out;

  float*    vals = (float*)d_ws;                     // PAD*NH f32 = 192 KB
  unsigned* offs = (unsigned*)(vals + PAD * NH);     // PAD*NH u32 = 192 KB
  int*      nnz  = (int*)(offs + PAD * NH);          // NH
  int*      perm = nnz + NH;                         // NH
  int*      cntw = perm + NH;                        // 8

  hipLaunchKernelGGL(count_nnz, dim3(NH / 8), dim3(512), 0, stream, Whh, nnz);
  hipLaunchKernelGGL(sort_rows, dim3(1), dim3(512), 0, stream, nnz, perm);
  hipLaunchKernelGGL(build_schedule, dim3(8), dim3(64), 0, stream,
                     Whh, perm, vals, offs, cntw);
  hipLaunchKernelGGL(esn_steps, dim3(BB), dim3(512), 0, stream,
                     x, h0, Wih, Whz, Wzh, vals, offs, perm, cntw, out);
}